// Round 4
// baseline (4384.662 us; speedup 1.0000x reference)
//
#include <hip/hip_runtime.h>
#include <hip/hip_bf16.h>
#include <math.h>

#define Bn 4096
#define Dd 768
#define INV_T 20.0f
#define EPSF 1e-6f
#define DG 4.8516519541e8f   // expf(20.0f): exact exp_ori diagonal

// ws layout (4-byte elements)
#define O_S      0        // 3*4096 row sums (ori_nodiag, gen, aug)
#define O_SMOA   12288    // same-masked (ori_nodiag + aug) sums
#define O_SMG    16384    // same-masked gen sums
#define O_DCO    20480
#define O_DAD    24576
#define O_LOSS   28672    // [0]=ad acc, [1]=co acc
#define O_CUR    28676    // uint[3] list cursors
#define ZERO_BYTES 131072
#define LIST_OFF   131072      // byte offset: 3 lists of LCAP uint2
#define LCAP       (1u << 20)
#define NB_OFF     33554432    // byte offset: bf16 normalized rows on|gn|an

typedef __attribute__((ext_vector_type(8))) short sh8;
typedef __attribute__((ext_vector_type(4))) float f32x4;

#define AS1 __attribute__((address_space(1)))
#define AS3 __attribute__((address_space(3)))

static __device__ __forceinline__ void gl_lds16(const void* g, void* l) {
    __builtin_amdgcn_global_load_lds((const AS1 void*)g, (AS3 void*)l, 16, 0, 0);
}

static __device__ __forceinline__ unsigned short f2b(float f) {
    unsigned int u = __float_as_uint(f);
    unsigned int r = (u + 0x7fffu + ((u >> 16) & 1u)) >> 16;  // RNE
    return (unsigned short)r;
}

// ---- normalize rows, write bf16 ----
__global__ void norm_kernel(const float* f0, const float* f1, const float* f2, unsigned short* nb) {
    int r = blockIdx.x, m = blockIdx.y, tid = threadIdx.x;
    const float* src = (m == 0 ? f0 : (m == 1 ? f1 : f2)) + (size_t)r * Dd;
    float x0 = src[tid], x1 = src[tid + 256], x2 = src[tid + 512];
    float v = x0 * x0 + x1 * x1 + x2 * x2;
    #pragma unroll
    for (int off = 1; off < 64; off <<= 1) v += __shfl_xor(v, off);
    __shared__ float wr[4];
    if ((tid & 63) == 0) wr[tid >> 6] = v;
    __syncthreads();
    float inv = rsqrtf(wr[0] + wr[1] + wr[2] + wr[3]);
    unsigned short* dst = nb + ((size_t)m * Bn + r) * Dd;
    dst[tid] = f2b(x0 * inv);
    dst[tid + 256] = f2b(x1 * inv);
    dst[tid + 512] = f2b(x2 * inv);
}

// ---- fused GEMM + exp row-sum + same-pair extraction.
// z selects B-operand (0:on 1:gn 2:an); A is always on.
// Swizzle: LDS slot (row, pos) holds global seg pos^((row>>1)&3) so that each
// 8-lane b128 phase covers 8 distinct 4-bank groups (conflict-free).
__launch_bounds__(256)
__global__ void gemm_rowsum(const unsigned short* nb, const int* tg, char* ws) {
    float* F = (float*)ws;
    unsigned int* cur = (unsigned int*)(F + O_CUR);
    uint2* lists = (uint2*)(ws + LIST_OFF);
    int z = blockIdx.z;
    const unsigned short* Ag = nb;
    const unsigned short* Bg = nb + (size_t)z * Bn * Dd;
    int m0 = blockIdx.y * 128, n0 = blockIdx.x * 128;
    int tid = threadIdx.x, lane = tid & 63, wave = tid >> 6;
    int wm = (wave >> 1) * 64, wn = (wave & 1) * 64;
    int lid = lane & 15, q = lane >> 4;
    __shared__ __align__(16) unsigned short Asm[128 * 32];
    __shared__ __align__(16) unsigned short Bsm[128 * 32];
    int c0 = tid, c1 = tid + 256;
    int row0 = c0 >> 2, sg0 = (c0 & 3) ^ ((row0 >> 1) & 3);
    int row1 = c1 >> 2, sg1 = (c1 & 3) ^ ((row1 >> 1) & 3);
    const unsigned short* gA0 = Ag + (size_t)(m0 + row0) * Dd + sg0 * 8;
    const unsigned short* gA1 = Ag + (size_t)(m0 + row1) * Dd + sg1 * 8;
    const unsigned short* gB0 = Bg + (size_t)(n0 + row0) * Dd + sg0 * 8;
    const unsigned short* gB1 = Bg + (size_t)(n0 + row1) * Dd + sg1 * 8;
    unsigned short* lA0 = &Asm[c0 * 8];
    unsigned short* lA1 = &Asm[c1 * 8];
    unsigned short* lB0 = &Bsm[c0 * 8];
    unsigned short* lB1 = &Bsm[c1 * 8];
    f32x4 acc[4][4] = {};
    for (int kt = 0; kt < Dd / 32; ++kt) {
        __syncthreads();
        gl_lds16(gA0 + kt * 32, lA0);
        gl_lds16(gA1 + kt * 32, lA1);
        gl_lds16(gB0 + kt * 32, lB0);
        gl_lds16(gB1 + kt * 32, lB1);
        __syncthreads();
        sh8 af[4], bf[4];
        #pragma unroll
        for (int i = 0; i < 4; ++i) {
            int r = wm + i * 16 + lid;
            af[i] = *(const sh8*)&Asm[r * 32 + ((q ^ ((r >> 1) & 3)) * 8)];
        }
        #pragma unroll
        for (int j = 0; j < 4; ++j) {
            int r = wn + j * 16 + lid;
            bf[j] = *(const sh8*)&Bsm[r * 32 + ((q ^ ((r >> 1) & 3)) * 8)];
        }
        #pragma unroll
        for (int i = 0; i < 4; ++i)
            #pragma unroll
            for (int j = 0; j < 4; ++j)
                acc[i][j] = __builtin_amdgcn_mfma_f32_16x16x32_bf16(af[i], bf[j], acc[i][j], 0, 0, 0);
    }
    // epilogue: e = exp(s/T); exclude ori diagonal; full row-sum + same-pair work
    int tcol[4];
    #pragma unroll
    for (int j = 0; j < 4; ++j) tcol[j] = tg[n0 + wn + j * 16 + lid];
    int smoff = (z == 1) ? O_SMG : O_SMOA;
    uint2* Lz = lists + (size_t)z * LCAP;
    #pragma unroll
    for (int i = 0; i < 4; ++i)
        #pragma unroll
        for (int reg = 0; reg < 4; ++reg) {
            int grow = m0 + wm + i * 16 + q * 4 + reg;
            int trow = tg[grow];
            float rs = 0.f;
            #pragma unroll
            for (int j = 0; j < 4; ++j) {
                int gcol = n0 + wn + j * 16 + lid;
                float x = acc[i][j][reg] * INV_T;
                float e = __expf(x);
                if (z == 0 && gcol == grow) e = 0.f;
                rs += e;
                if (tcol[j] == trow) {
                    atomicAdd(&F[smoff + grow], e);
                    unsigned int idx = atomicAdd(&cur[z], 1u);
                    if (idx < LCAP) Lz[idx] = make_uint2((unsigned)grow, __float_as_uint(x));
                }
            }
            #pragma unroll
            for (int off = 1; off < 16; off <<= 1) rs += __shfl_xor(rs, off);
            if (lid == 0) atomicAdd(&F[O_S + z * Bn + grow], rs);
        }
}

__global__ void denom_kernel(float* F) {
    int i = blockIdx.x * 256 + threadIdx.x;
    if (i < Bn) {
        float son = F[O_S + i], sgen = F[O_S + Bn + i], saug = F[O_S + 2 * Bn + i];
        F[O_DCO + i] = (son + saug - F[O_SMOA + i]) + sgen + EPSF;
        F[O_DAD + i] = (sgen - F[O_SMG + i]) + saug + son + DG + EPSF;
    }
}

// ---- flat loss pass over the 3 extracted pair lists ----
__launch_bounds__(256)
__global__ void loss_kernel(char* ws) {
    float* F = (float*)ws;
    const unsigned int* cur = (const unsigned int*)(F + O_CUR);
    const uint2* lists = (const uint2*)(ws + LIST_OFF);
    float a0 = 0.f, a1 = 0.f;
    int stride = gridDim.x * 256;
    for (int z = 0; z < 3; ++z) {
        unsigned int n = cur[z]; if (n > LCAP) n = LCAP;
        const uint2* Lz = lists + (size_t)z * LCAP;
        for (unsigned int idx = blockIdx.x * 256 + threadIdx.x; idx < n; idx += stride) {
            uint2 en = Lz[idx];
            int i = (int)en.x;
            float e = __expf(__uint_as_float(en.y));
            if (z == 1) a0 += -__logf(e / (e + F[O_DAD + i]) + EPSF);
            else        a1 += -__logf(e / (e + F[O_DCO + i]) + EPSF);
        }
    }
    #pragma unroll
    for (int off = 1; off < 64; off <<= 1) { a0 += __shfl_xor(a0, off); a1 += __shfl_xor(a1, off); }
    __shared__ float r0[4], r1[4];
    int tid = threadIdx.x;
    if ((tid & 63) == 0) { r0[tid >> 6] = a0; r1[tid >> 6] = a1; }
    __syncthreads();
    if (tid == 0) {
        atomicAdd(&F[O_LOSS + 0], r0[0] + r0[1] + r0[2] + r0[3]);
        atomicAdd(&F[O_LOSS + 1], r1[0] + r1[1] + r1[2] + r1[3]);
    }
}

__global__ void final_kernel(const float* F, float* out) {
    out[0] = F[O_LOSS + 0] * (1.0f / Bn);  // ad_loss
    out[1] = F[O_LOSS + 1] * (1.0f / Bn);  // co_loss
}

extern "C" void kernel_launch(void* const* d_in, const int* in_sizes, int n_in,
                              void* d_out, int out_size, void* d_ws, size_t ws_size,
                              hipStream_t stream) {
    const float* f0 = (const float*)d_in[0];
    const float* f1 = (const float*)d_in[1];
    const float* f2 = (const float*)d_in[2];
    const int* tg = (const int*)d_in[3];
    char* ws = (char*)d_ws;
    float* F = (float*)d_ws;
    unsigned short* nb = (unsigned short*)(ws + NB_OFF);
    float* out = (float*)d_out;

    hipMemsetAsync(d_ws, 0, ZERO_BYTES, stream);
    norm_kernel<<<dim3(Bn, 3), 256, 0, stream>>>(f0, f1, f2, nb);
    gemm_rowsum<<<dim3(32, 32, 3), 256, 0, stream>>>(nb, tg, ws);
    denom_kernel<<<Bn / 256, 256, 0, stream>>>(F);
    loss_kernel<<<128, 256, 0, stream>>>(ws);
    final_kernel<<<1, 1, 0, stream>>>(F, out);
}

// Round 5
// 334.879 us; speedup vs baseline: 13.0933x; 13.0933x over previous
//
#include <hip/hip_runtime.h>
#include <hip/hip_bf16.h>
#include <math.h>

#define Bn 4096
#define Dd 768
#define INV_T 20.0f
#define EPSF 1e-6f
#define DG 4.8516519541e8f   // expf(20.0f): exact exp_ori diagonal

// ws layout (4-byte elements)
#define O_S      0        // 3*4096 row sums (ori_nodiag, gen, aug)
#define O_SMOA   12288    // same-masked (ori_nodiag + aug) sums
#define O_SMG    16384    // same-masked gen sums
#define O_DCO    20480
#define O_DAD    24576
#define O_LOSS   28672    // [0]=ad acc, [1]=co acc
#define O_CUR    28676    // uint[3] list cursors
#define ZERO_BYTES 131072
#define LIST_OFF   131072      // byte offset: 3 lists of LCAP uint2
#define LCAP       (1u << 20)
#define NB_OFF     33554432    // byte offset: bf16 normalized rows on|gn|an

typedef __attribute__((ext_vector_type(8))) short sh8;
typedef __attribute__((ext_vector_type(4))) float f32x4;

#define AS1 __attribute__((address_space(1)))
#define AS3 __attribute__((address_space(3)))

static __device__ __forceinline__ void gl_lds16(const void* g, void* l) {
    __builtin_amdgcn_global_load_lds((const AS1 void*)g, (AS3 void*)l, 16, 0, 0);
}

static __device__ __forceinline__ unsigned short f2b(float f) {
    unsigned int u = __float_as_uint(f);
    unsigned int r = (u + 0x7fffu + ((u >> 16) & 1u)) >> 16;  // RNE
    return (unsigned short)r;
}

// ---- normalize rows, write bf16 ----
__global__ void norm_kernel(const float* f0, const float* f1, const float* f2, unsigned short* nb) {
    int r = blockIdx.x, m = blockIdx.y, tid = threadIdx.x;
    const float* src = (m == 0 ? f0 : (m == 1 ? f1 : f2)) + (size_t)r * Dd;
    float x0 = src[tid], x1 = src[tid + 256], x2 = src[tid + 512];
    float v = x0 * x0 + x1 * x1 + x2 * x2;
    #pragma unroll
    for (int off = 1; off < 64; off <<= 1) v += __shfl_xor(v, off);
    __shared__ float wr[4];
    if ((tid & 63) == 0) wr[tid >> 6] = v;
    __syncthreads();
    float inv = rsqrtf(wr[0] + wr[1] + wr[2] + wr[3]);
    unsigned short* dst = nb + ((size_t)m * Bn + r) * Dd;
    dst[tid] = f2b(x0 * inv);
    dst[tid + 256] = f2b(x1 * inv);
    dst[tid + 512] = f2b(x2 * inv);
}

// ---- fused GEMM + exp row-sum + same-pair extraction.
// z selects B-operand (0:on 1:gn 2:an); A is always on.
// LDS swizzle pos = seg ^ ((row>>1)&3): verified conflict-free (R4: SQ_LDS_BANK_CONFLICT=0).
// Pair extraction uses ONE cursor atomic per wave (prefix-scan aggregated) --
// the per-lane returning atomic in R4 serialized the whole GPU (4.3 ms).
__launch_bounds__(256)
__global__ void gemm_rowsum(const unsigned short* nb, const int* tg, char* ws) {
    float* F = (float*)ws;
    unsigned int* cur = (unsigned int*)(F + O_CUR);
    uint2* lists = (uint2*)(ws + LIST_OFF);
    int z = blockIdx.z;
    const unsigned short* Ag = nb;
    const unsigned short* Bg = nb + (size_t)z * Bn * Dd;
    int m0 = blockIdx.y * 128, n0 = blockIdx.x * 128;
    int tid = threadIdx.x, lane = tid & 63, wave = tid >> 6;
    int wm = (wave >> 1) * 64, wn = (wave & 1) * 64;
    int lid = lane & 15, q = lane >> 4;
    __shared__ __align__(16) unsigned short Asm[128 * 32];
    __shared__ __align__(16) unsigned short Bsm[128 * 32];
    int c0 = tid, c1 = tid + 256;
    int row0 = c0 >> 2, sg0 = (c0 & 3) ^ ((row0 >> 1) & 3);
    int row1 = c1 >> 2, sg1 = (c1 & 3) ^ ((row1 >> 1) & 3);
    const unsigned short* gA0 = Ag + (size_t)(m0 + row0) * Dd + sg0 * 8;
    const unsigned short* gA1 = Ag + (size_t)(m0 + row1) * Dd + sg1 * 8;
    const unsigned short* gB0 = Bg + (size_t)(n0 + row0) * Dd + sg0 * 8;
    const unsigned short* gB1 = Bg + (size_t)(n0 + row1) * Dd + sg1 * 8;
    unsigned short* lA0 = &Asm[c0 * 8];
    unsigned short* lA1 = &Asm[c1 * 8];
    unsigned short* lB0 = &Bsm[c0 * 8];
    unsigned short* lB1 = &Bsm[c1 * 8];
    f32x4 acc[4][4] = {};
    for (int kt = 0; kt < Dd / 32; ++kt) {
        __syncthreads();
        gl_lds16(gA0 + kt * 32, lA0);
        gl_lds16(gA1 + kt * 32, lA1);
        gl_lds16(gB0 + kt * 32, lB0);
        gl_lds16(gB1 + kt * 32, lB1);
        __syncthreads();
        sh8 af[4], bf[4];
        #pragma unroll
        for (int i = 0; i < 4; ++i) {
            int r = wm + i * 16 + lid;
            af[i] = *(const sh8*)&Asm[r * 32 + ((q ^ ((r >> 1) & 3)) * 8)];
        }
        #pragma unroll
        for (int j = 0; j < 4; ++j) {
            int r = wn + j * 16 + lid;
            bf[j] = *(const sh8*)&Bsm[r * 32 + ((q ^ ((r >> 1) & 3)) * 8)];
        }
        #pragma unroll
        for (int i = 0; i < 4; ++i)
            #pragma unroll
            for (int j = 0; j < 4; ++j)
                acc[i][j] = __builtin_amdgcn_mfma_f32_16x16x32_bf16(af[i], bf[j], acc[i][j], 0, 0, 0);
    }
    // ---- epilogue phase 1: row sums, masked sums, match counts ----
    int tcol[4];
    #pragma unroll
    for (int j = 0; j < 4; ++j) tcol[j] = tg[n0 + wn + j * 16 + lid];
    int smoff = (z == 1) ? O_SMG : O_SMOA;
    unsigned int mcnt = 0;
    #pragma unroll
    for (int i = 0; i < 4; ++i)
        #pragma unroll
        for (int reg = 0; reg < 4; ++reg) {
            int grow = m0 + wm + i * 16 + q * 4 + reg;
            int trow = tg[grow];
            float rs = 0.f, ms = 0.f;
            #pragma unroll
            for (int j = 0; j < 4; ++j) {
                int gcol = n0 + wn + j * 16 + lid;
                float x = acc[i][j][reg] * INV_T;
                float e = __expf(x);
                if (z == 0 && gcol == grow) e = 0.f;
                rs += e;
                if (tcol[j] == trow) { ms += e; mcnt++; }
            }
            #pragma unroll
            for (int off = 1; off < 16; off <<= 1) {
                rs += __shfl_xor(rs, off);
                ms += __shfl_xor(ms, off);
            }
            if (lid == 0) {
                atomicAdd(&F[O_S + z * Bn + grow], rs);
                atomicAdd(&F[smoff + grow], ms);
            }
        }
    // ---- wave-aggregated list reservation: 1 atomic per wave ----
    unsigned int pre = mcnt;
    #pragma unroll
    for (int off = 1; off < 64; off <<= 1) {
        unsigned int t = __shfl_up(pre, off);
        if (lane >= off) pre += t;
    }
    unsigned int total = __shfl(pre, 63);
    unsigned int excl = pre - mcnt;
    unsigned int base = 0;
    if (lane == 63 && total) base = atomicAdd(&cur[z], total);
    base = __shfl(base, 63);
    // ---- epilogue phase 2: write matches at reserved slots ----
    if (total) {
        uint2* Lz = lists + (size_t)z * LCAP;
        unsigned int slot = base + excl;
        #pragma unroll
        for (int i = 0; i < 4; ++i)
            #pragma unroll
            for (int reg = 0; reg < 4; ++reg) {
                int grow = m0 + wm + i * 16 + q * 4 + reg;
                int trow = tg[grow];
                #pragma unroll
                for (int j = 0; j < 4; ++j) {
                    if (tcol[j] == trow) {
                        float x = acc[i][j][reg] * INV_T;
                        if (slot < LCAP) Lz[slot] = make_uint2((unsigned)grow, __float_as_uint(x));
                        slot++;
                    }
                }
            }
    }
}

__global__ void denom_kernel(float* F) {
    int i = blockIdx.x * 256 + threadIdx.x;
    if (i < Bn) {
        float son = F[O_S + i], sgen = F[O_S + Bn + i], saug = F[O_S + 2 * Bn + i];
        F[O_DCO + i] = (son + saug - F[O_SMOA + i]) + sgen + EPSF;
        F[O_DAD + i] = (sgen - F[O_SMG + i]) + saug + son + DG + EPSF;
    }
}

// ---- flat loss pass over the 3 extracted pair lists ----
__launch_bounds__(256)
__global__ void loss_kernel(char* ws) {
    float* F = (float*)ws;
    const unsigned int* cur = (const unsigned int*)(F + O_CUR);
    const uint2* lists = (const uint2*)(ws + LIST_OFF);
    float a0 = 0.f, a1 = 0.f;
    int stride = gridDim.x * 256;
    for (int z = 0; z < 3; ++z) {
        unsigned int n = cur[z]; if (n > LCAP) n = LCAP;
        const uint2* Lz = lists + (size_t)z * LCAP;
        for (unsigned int idx = blockIdx.x * 256 + threadIdx.x; idx < n; idx += stride) {
            uint2 en = Lz[idx];
            int i = (int)en.x;
            float e = __expf(__uint_as_float(en.y));
            if (z == 1) a0 += -__logf(e / (e + F[O_DAD + i]) + EPSF);
            else        a1 += -__logf(e / (e + F[O_DCO + i]) + EPSF);
        }
    }
    #pragma unroll
    for (int off = 1; off < 64; off <<= 1) { a0 += __shfl_xor(a0, off); a1 += __shfl_xor(a1, off); }
    __shared__ float r0[4], r1[4];
    int tid = threadIdx.x;
    if ((tid & 63) == 0) { r0[tid >> 6] = a0; r1[tid >> 6] = a1; }
    __syncthreads();
    if (tid == 0) {
        atomicAdd(&F[O_LOSS + 0], r0[0] + r0[1] + r0[2] + r0[3]);
        atomicAdd(&F[O_LOSS + 1], r1[0] + r1[1] + r1[2] + r1[3]);
    }
}

__global__ void final_kernel(const float* F, float* out) {
    out[0] = F[O_LOSS + 0] * (1.0f / Bn);  // ad_loss
    out[1] = F[O_LOSS + 1] * (1.0f / Bn);  // co_loss
}

extern "C" void kernel_launch(void* const* d_in, const int* in_sizes, int n_in,
                              void* d_out, int out_size, void* d_ws, size_t ws_size,
                              hipStream_t stream) {
    const float* f0 = (const float*)d_in[0];
    const float* f1 = (const float*)d_in[1];
    const float* f2 = (const float*)d_in[2];
    const int* tg = (const int*)d_in[3];
    char* ws = (char*)d_ws;
    float* F = (float*)d_ws;
    unsigned short* nb = (unsigned short*)(ws + NB_OFF);
    float* out = (float*)d_out;

    hipMemsetAsync(d_ws, 0, ZERO_BYTES, stream);
    norm_kernel<<<dim3(Bn, 3), 256, 0, stream>>>(f0, f1, f2, nb);
    gemm_rowsum<<<dim3(32, 32, 3), 256, 0, stream>>>(nb, tg, ws);
    denom_kernel<<<Bn / 256, 256, 0, stream>>>(F);
    loss_kernel<<<128, 256, 0, stream>>>(ws);
    final_kernel<<<1, 1, 0, stream>>>(F, out);
}

// Round 6
// 255.299 us; speedup vs baseline: 17.1746x; 1.3117x over previous
//
#include <hip/hip_runtime.h>
#include <hip/hip_bf16.h>
#include <math.h>

#define Bn 4096
#define Dd 768
#define INV_T 20.0f
#define EPSF 1e-6f
#define DG 4.8516519541e8f   // expf(20.0f): exact exp_ori diagonal

// ws layout (4-byte elements)
#define O_S      0        // 3*4096 row sums (ori_nodiag, gen, aug)
#define O_SMOA   12288    // same-masked (ori_nodiag + aug) sums
#define O_SMG    16384    // same-masked gen sums
#define O_DCO    20480
#define O_DAD    24576
#define O_LOSS   28672    // [0]=ad acc, [1]=co acc
#define O_P      28676    // uint: total pairs per z (= sum cnt^2)
#define O_CNT    28800    // uint[128]
#define O_START  28928    // uint[128]
#define O_CURSOR 29056    // uint[128]
#define O_PB     29184    // uint[128] class pair base
#define O_RANK   29312    // uint[4096]
#define O_RSB    33408    // uint[4096] row slot base
#define ZERO_BYTES 163840
#define LIST_OFF   262144      // byte offset: 3 lists of LCAP uint2
#define LCAP       (1u << 19)
#define NB_OFF     33554432    // byte offset: bf16 normalized rows on|gn|an

typedef __attribute__((ext_vector_type(8))) short sh8;
typedef __attribute__((ext_vector_type(4))) float f32x4;

#define AS1 __attribute__((address_space(1)))
#define AS3 __attribute__((address_space(3)))

static __device__ __forceinline__ void gl_lds16(const void* g, void* l) {
    __builtin_amdgcn_global_load_lds((const AS1 void*)g, (AS3 void*)l, 16, 0, 0);
}

static __device__ __forceinline__ unsigned short f2b(float f) {
    unsigned int u = __float_as_uint(f);
    unsigned int r = (u + 0x7fffu + ((u >> 16) & 1u)) >> 16;  // RNE
    return (unsigned short)r;
}

// ---- normalize rows, write bf16 ----
__global__ void norm_kernel(const float* f0, const float* f1, const float* f2, unsigned short* nb) {
    int r = blockIdx.x, m = blockIdx.y, tid = threadIdx.x;
    const float* src = (m == 0 ? f0 : (m == 1 ? f1 : f2)) + (size_t)r * Dd;
    float x0 = src[tid], x1 = src[tid + 256], x2 = src[tid + 512];
    float v = x0 * x0 + x1 * x1 + x2 * x2;
    #pragma unroll
    for (int off = 1; off < 64; off <<= 1) v += __shfl_xor(v, off);
    __shared__ float wr[4];
    if ((tid & 63) == 0) wr[tid >> 6] = v;
    __syncthreads();
    float inv = rsqrtf(wr[0] + wr[1] + wr[2] + wr[3]);
    unsigned short* dst = nb + ((size_t)m * Bn + r) * Dd;
    dst[tid] = f2b(x0 * inv);
    dst[tid + 256] = f2b(x1 * inv);
    dst[tid + 512] = f2b(x2 * inv);
}

// ---- class histogram / prefix / scatter+rank ----
__global__ void hist_kernel(const int* tg, unsigned int* I) {
    int i = blockIdx.x * 256 + threadIdx.x;
    if (i < Bn) atomicAdd(&I[O_CNT + tg[i]], 1u);
}
__global__ void prefix_kernel(unsigned int* I) {
    unsigned int acc = 0, pacc = 0;
    for (int c = 0; c < 128; ++c) {
        I[O_START + c] = acc; I[O_CURSOR + c] = acc; I[O_PB + c] = pacc;
        unsigned int n = I[O_CNT + c];
        acc += n; pacc += n * n;
    }
    I[O_P] = pacc;
}
__global__ void scatter_kernel(const int* tg, unsigned int* I) {
    int i = blockIdx.x * 256 + threadIdx.x;
    if (i < Bn) {
        int c = tg[i];
        unsigned int pos = atomicAdd(&I[O_CURSOR + c], 1u);
        unsigned int r = pos - I[O_START + c];
        I[O_RANK + i] = r;
        I[O_RSB + i] = I[O_PB + c] + r * I[O_CNT + c];
    }
}

// ---- fused GEMM + exp row-sum + masked sums + deterministic pair extraction.
// z selects B-operand (0:on 1:gn 2:an); A is always on.
// LDS swizzle pos = seg ^ ((row>>1)&3): conflict-free (R4/R5: SQ_LDS_BANK_CONFLICT=0).
// Pair slots are deterministic (rowSlotBase[i] + rank[j]) -> fire-and-forget
// stores, ZERO returning atomics (R4: per-lane cursor = 4.3ms; R5: per-wave
// cursor = +130us. Returning same-address atomics serialize the grid.)
__launch_bounds__(256)
__global__ void gemm_rowsum(const unsigned short* nb, const int* tg, char* ws) {
    float* F = (float*)ws;
    const unsigned int* I = (const unsigned int*)ws;
    uint2* lists = (uint2*)(ws + LIST_OFF);
    int z = blockIdx.z;
    const unsigned short* Ag = nb;
    const unsigned short* Bg = nb + (size_t)z * Bn * Dd;
    int m0 = blockIdx.y * 128, n0 = blockIdx.x * 128;
    int tid = threadIdx.x, lane = tid & 63, wave = tid >> 6;
    int wm = (wave >> 1) * 64, wn = (wave & 1) * 64;
    int lid = lane & 15, q = lane >> 4;
    __shared__ __align__(16) unsigned short Asm[128 * 32];
    __shared__ __align__(16) unsigned short Bsm[128 * 32];
    int c0 = tid, c1 = tid + 256;
    int row0 = c0 >> 2, sg0 = (c0 & 3) ^ ((row0 >> 1) & 3);
    int row1 = c1 >> 2, sg1 = (c1 & 3) ^ ((row1 >> 1) & 3);
    const unsigned short* gA0 = Ag + (size_t)(m0 + row0) * Dd + sg0 * 8;
    const unsigned short* gA1 = Ag + (size_t)(m0 + row1) * Dd + sg1 * 8;
    const unsigned short* gB0 = Bg + (size_t)(n0 + row0) * Dd + sg0 * 8;
    const unsigned short* gB1 = Bg + (size_t)(n0 + row1) * Dd + sg1 * 8;
    unsigned short* lA0 = &Asm[c0 * 8];
    unsigned short* lA1 = &Asm[c1 * 8];
    unsigned short* lB0 = &Bsm[c0 * 8];
    unsigned short* lB1 = &Bsm[c1 * 8];
    f32x4 acc[4][4] = {};
    for (int kt = 0; kt < Dd / 32; ++kt) {
        __syncthreads();
        gl_lds16(gA0 + kt * 32, lA0);
        gl_lds16(gA1 + kt * 32, lA1);
        gl_lds16(gB0 + kt * 32, lB0);
        gl_lds16(gB1 + kt * 32, lB1);
        __syncthreads();
        sh8 af[4], bf[4];
        #pragma unroll
        for (int i = 0; i < 4; ++i) {
            int r = wm + i * 16 + lid;
            af[i] = *(const sh8*)&Asm[r * 32 + ((q ^ ((r >> 1) & 3)) * 8)];
        }
        #pragma unroll
        for (int j = 0; j < 4; ++j) {
            int r = wn + j * 16 + lid;
            bf[j] = *(const sh8*)&Bsm[r * 32 + ((q ^ ((r >> 1) & 3)) * 8)];
        }
        #pragma unroll
        for (int i = 0; i < 4; ++i)
            #pragma unroll
            for (int j = 0; j < 4; ++j)
                acc[i][j] = __builtin_amdgcn_mfma_f32_16x16x32_bf16(af[i], bf[j], acc[i][j], 0, 0, 0);
    }
    // ---- epilogue: row sums, masked sums, deterministic pair stores ----
    int tcol[4]; unsigned int rkc[4];
    #pragma unroll
    for (int j = 0; j < 4; ++j) {
        int gc = n0 + wn + j * 16 + lid;
        tcol[j] = tg[gc];
        rkc[j] = I[O_RANK + gc];
    }
    int smoff = (z == 1) ? O_SMG : O_SMOA;
    uint2* Lz = lists + (size_t)z * LCAP;
    #pragma unroll
    for (int i = 0; i < 4; ++i)
        #pragma unroll
        for (int reg = 0; reg < 4; ++reg) {
            int grow = m0 + wm + i * 16 + q * 4 + reg;
            int trow = tg[grow];
            unsigned int rsb = I[O_RSB + grow];
            float rs = 0.f, ms = 0.f;
            #pragma unroll
            for (int j = 0; j < 4; ++j) {
                int gcol = n0 + wn + j * 16 + lid;
                float x = acc[i][j][reg] * INV_T;
                float e = __expf(x);
                if (z == 0 && gcol == grow) e = 0.f;
                rs += e;
                if (tcol[j] == trow) {
                    ms += e;
                    unsigned int slot = rsb + rkc[j];
                    if (slot < LCAP) Lz[slot] = make_uint2((unsigned)grow, __float_as_uint(x));
                }
            }
            #pragma unroll
            for (int off = 1; off < 16; off <<= 1) {
                rs += __shfl_xor(rs, off);
                ms += __shfl_xor(ms, off);
            }
            if (lid == 0) {
                atomicAdd(&F[O_S + z * Bn + grow], rs);
                atomicAdd(&F[smoff + grow], ms);
            }
        }
}

__global__ void denom_kernel(float* F) {
    int i = blockIdx.x * 256 + threadIdx.x;
    if (i < Bn) {
        float son = F[O_S + i], sgen = F[O_S + Bn + i], saug = F[O_S + 2 * Bn + i];
        F[O_DCO + i] = (son + saug - F[O_SMOA + i]) + sgen + EPSF;
        F[O_DAD + i] = (sgen - F[O_SMG + i]) + saug + son + DG + EPSF;
    }
}

// ---- flat loss pass over the 3 extracted pair lists ----
__launch_bounds__(256)
__global__ void loss_kernel(char* ws) {
    float* F = (float*)ws;
    const unsigned int* I = (const unsigned int*)ws;
    const uint2* lists = (const uint2*)(ws + LIST_OFF);
    unsigned int n = I[O_P]; if (n > LCAP) n = LCAP;
    float a0 = 0.f, a1 = 0.f;
    int stride = gridDim.x * 256;
    for (int z = 0; z < 3; ++z) {
        const uint2* Lz = lists + (size_t)z * LCAP;
        for (unsigned int idx = blockIdx.x * 256 + threadIdx.x; idx < n; idx += stride) {
            uint2 en = Lz[idx];
            int i = (int)en.x;
            float e = __expf(__uint_as_float(en.y));
            if (z == 1) a0 += -__logf(e / (e + F[O_DAD + i]) + EPSF);
            else        a1 += -__logf(e / (e + F[O_DCO + i]) + EPSF);
        }
    }
    #pragma unroll
    for (int off = 1; off < 64; off <<= 1) { a0 += __shfl_xor(a0, off); a1 += __shfl_xor(a1, off); }
    __shared__ float r0[4], r1[4];
    int tid = threadIdx.x;
    if ((tid & 63) == 0) { r0[tid >> 6] = a0; r1[tid >> 6] = a1; }
    __syncthreads();
    if (tid == 0) {
        atomicAdd(&F[O_LOSS + 0], r0[0] + r0[1] + r0[2] + r0[3]);
        atomicAdd(&F[O_LOSS + 1], r1[0] + r1[1] + r1[2] + r1[3]);
    }
}

__global__ void final_kernel(const float* F, float* out) {
    out[0] = F[O_LOSS + 0] * (1.0f / Bn);  // ad_loss
    out[1] = F[O_LOSS + 1] * (1.0f / Bn);  // co_loss
}

extern "C" void kernel_launch(void* const* d_in, const int* in_sizes, int n_in,
                              void* d_out, int out_size, void* d_ws, size_t ws_size,
                              hipStream_t stream) {
    const float* f0 = (const float*)d_in[0];
    const float* f1 = (const float*)d_in[1];
    const float* f2 = (const float*)d_in[2];
    const int* tg = (const int*)d_in[3];
    char* ws = (char*)d_ws;
    float* F = (float*)d_ws;
    unsigned int* I = (unsigned int*)d_ws;
    unsigned short* nb = (unsigned short*)(ws + NB_OFF);
    float* out = (float*)d_out;

    hipMemsetAsync(d_ws, 0, ZERO_BYTES, stream);
    norm_kernel<<<dim3(Bn, 3), 256, 0, stream>>>(f0, f1, f2, nb);
    hist_kernel<<<Bn / 256, 256, 0, stream>>>(tg, I);
    prefix_kernel<<<1, 1, 0, stream>>>(I);
    scatter_kernel<<<Bn / 256, 256, 0, stream>>>(tg, I);
    gemm_rowsum<<<dim3(32, 32, 3), 256, 0, stream>>>(nb, tg, ws);
    denom_kernel<<<Bn / 256, 256, 0, stream>>>(F);
    loss_kernel<<<256, 256, 0, stream>>>(ws);
    final_kernel<<<1, 1, 0, stream>>>(F, out);
}